// Round 1
// baseline (326.999 us; speedup 1.0000x reference)
//
#include <hip/hip_runtime.h>
#include <math.h>

// Problem dims (fixed by reference setup_inputs)
#define I_DIM 1024
#define S_DIM 512
#define O_DIM 1024
#define T_DIM 2048
#define B_SZ 4
#define M_ROWS (B_SZ * T_DIM)   // 8192 rows for both GEMMs
#define EPSF 1e-6f

// ---------------------------------------------------------------------------
// Kernel 1: per-row RMS scale.  rs[row] = rsqrt(mean(u[row,:]^2) + eps)
// One block (256 threads) per row of 1024 floats; float4 loads.
// ---------------------------------------------------------------------------
__global__ void rms_rows(const float* __restrict__ u, float* __restrict__ rs) {
    const int row = blockIdx.x;
    const float4* up4 = reinterpret_cast<const float4*>(u + (size_t)row * I_DIM);
    float4 v = up4[threadIdx.x];
    float ss = v.x * v.x + v.y * v.y + v.z * v.z + v.w * v.w;
    // wave64 reduce
    #pragma unroll
    for (int off = 32; off > 0; off >>= 1) ss += __shfl_down(ss, off, 64);
    __shared__ float partial[4];
    const int wave = threadIdx.x >> 6;
    if ((threadIdx.x & 63) == 0) partial[wave] = ss;
    __syncthreads();
    if (threadIdx.x == 0) {
        float tot = partial[0] + partial[1] + partial[2] + partial[3];
        rs[row] = rsqrtf(tot * (1.0f / I_DIM) + EPSF);
    }
}

// ---------------------------------------------------------------------------
// Kernel 2/4: fp32 tiled GEMM  C[M,N] = A[M,K] * B[K,N] (+ bias[N])
// 64x64 tile, BK=16, 256 threads, 4x4 micro-tile per thread.
// SCALE_A: A element (m,k) scaled by rs[m]*nw[k]  (fused RMSNorm for GEMM1).
// ---------------------------------------------------------------------------
#define BM 64
#define BN 64
#define BK 16
#define LDP 68   // padded leading dim (keeps 16B alignment, breaks bank stride)

template <bool SCALE_A, bool BIAS>
__global__ __launch_bounds__(256)
void gemm64(const float* __restrict__ A, const float* __restrict__ B,
            float* __restrict__ Cout, int M, int N, int K,
            const float* __restrict__ rs, const float* __restrict__ nw,
            const float* __restrict__ bias) {
    __shared__ float As[BK][LDP];   // As[k][m]
    __shared__ float Bs[BK][LDP];   // Bs[k][n]

    const int tid = threadIdx.x;
    const int tx = tid & 15;        // n quad
    const int ty = tid >> 4;        // m quad
    const int m0 = blockIdx.y * BM;
    const int n0 = blockIdx.x * BN;

    // A-load mapping: thread -> (m_local = tid/4, kq = tid%4), float4 over k
    const int a_m = tid >> 2;
    const int a_kq = (tid & 3) * 4;
    // B-load mapping: thread -> (k_local = tid/16, nq = tid%16), float4 over n
    const int b_k = tid >> 4;
    const int b_n = (tid & 15) * 4;

    float c[4][4];
    #pragma unroll
    for (int i = 0; i < 4; ++i)
        #pragma unroll
        for (int j = 0; j < 4; ++j) c[i][j] = 0.0f;

    float a_scale_row = 1.0f;
    if (SCALE_A) a_scale_row = rs[m0 + a_m];

    for (int k0 = 0; k0 < K; k0 += BK) {
        // --- stage A tile ---
        float4 av = *reinterpret_cast<const float4*>(&A[(size_t)(m0 + a_m) * K + k0 + a_kq]);
        if (SCALE_A) {
            av.x *= a_scale_row * nw[k0 + a_kq + 0];
            av.y *= a_scale_row * nw[k0 + a_kq + 1];
            av.z *= a_scale_row * nw[k0 + a_kq + 2];
            av.w *= a_scale_row * nw[k0 + a_kq + 3];
        }
        As[a_kq + 0][a_m] = av.x;
        As[a_kq + 1][a_m] = av.y;
        As[a_kq + 2][a_m] = av.z;
        As[a_kq + 3][a_m] = av.w;
        // --- stage B tile ---
        float4 bv = *reinterpret_cast<const float4*>(&B[(size_t)(k0 + b_k) * N + n0 + b_n]);
        *reinterpret_cast<float4*>(&Bs[b_k][b_n]) = bv;

        __syncthreads();

        #pragma unroll
        for (int k = 0; k < BK; ++k) {
            float4 a4 = *reinterpret_cast<const float4*>(&As[k][ty * 4]);
            float4 b4 = *reinterpret_cast<const float4*>(&Bs[k][tx * 4]);
            const float ar[4] = {a4.x, a4.y, a4.z, a4.w};
            const float br[4] = {b4.x, b4.y, b4.z, b4.w};
            #pragma unroll
            for (int i = 0; i < 4; ++i)
                #pragma unroll
                for (int j = 0; j < 4; ++j)
                    c[i][j] = fmaf(ar[i], br[j], c[i][j]);
        }
        __syncthreads();
    }

    // --- write out ---
    #pragma unroll
    for (int i = 0; i < 4; ++i) {
        float4 o;
        o.x = c[i][0]; o.y = c[i][1]; o.z = c[i][2]; o.w = c[i][3];
        if (BIAS) {
            const float4 d4 = *reinterpret_cast<const float4*>(&bias[n0 + tx * 4]);
            o.x += d4.x; o.y += d4.y; o.z += d4.z; o.w += d4.w;
        }
        *reinterpret_cast<float4*>(&Cout[(size_t)(m0 + ty * 4 + i) * N + n0 + tx * 4]) = o;
    }
}

// ---------------------------------------------------------------------------
// Kernel 3: in-place linear scan over t.
// x[b,t,s] = a[s]*x[b,t-1,s] + dts[s]*up[b,t,s]   (up buffer overwritten)
// One thread per (b,s): 2048 threads. Also writes final state to xlast.
// ---------------------------------------------------------------------------
__global__ void scan_kernel(float* __restrict__ up, const float* __restrict__ dt,
                            const float* __restrict__ Avec, float* __restrict__ xlast) {
    const int gid = blockIdx.x * blockDim.x + threadIdx.x;  // 0..2047
    const int b = gid >> 9;
    const int s = gid & 511;
    const float dts = 1.0f / (1.0f + expf(-dt[s]));
    const float a = expf(-dts * fabsf(Avec[s]));

    float x = 0.0f;
    const size_t base = (size_t)b * T_DIM * S_DIM + s;
    for (int t = 0; t < T_DIM; t += 8) {
        float v[8];
        #pragma unroll
        for (int j = 0; j < 8; ++j) v[j] = up[base + (size_t)(t + j) * S_DIM];
        #pragma unroll
        for (int j = 0; j < 8; ++j) { x = fmaf(a, x, dts * v[j]); v[j] = x; }
        #pragma unroll
        for (int j = 0; j < 8; ++j) up[base + (size_t)(t + j) * S_DIM] = v[j];
    }
    xlast[b * S_DIM + s] = x;
}

// ---------------------------------------------------------------------------
extern "C" void kernel_launch(void* const* d_in, const int* in_sizes, int n_in,
                              void* d_out, int out_size, void* d_ws, size_t ws_size,
                              hipStream_t stream) {
    const float* u    = (const float*)d_in[0];   // [B,T,I]
    const float* dt   = (const float*)d_in[1];   // [S]
    const float* Avec = (const float*)d_in[2];   // [S]
    const float* Bmat = (const float*)d_in[3];   // [I,S]
    const float* Cmat = (const float*)d_in[4];   // [S,O]
    const float* Dvec = (const float*)d_in[5];   // [O]
    const float* nw   = (const float*)d_in[6];   // [I]

    float* y     = (float*)d_out;                          // [B,T,O]
    float* xlast = y + (size_t)M_ROWS * O_DIM;             // [B,S]

    float* rs = (float*)d_ws;                              // [8192] row scales
    float* up = (float*)((char*)d_ws + 65536);             // [B,T,S] = 16.8 MB

    // 1. per-row RMS scale
    rms_rows<<<M_ROWS, 256, 0, stream>>>(u, rs);

    // 2. GEMM1: up[b*T+t, s] = sum_i (u*rs*nw)[m,i] * Bmat[i,s]
    dim3 g1(S_DIM / BN, M_ROWS / BM);
    gemm64<true, false><<<g1, 256, 0, stream>>>(u, Bmat, up, M_ROWS, S_DIM, I_DIM,
                                                rs, nw, nullptr);

    // 3. linear scan over t (in place), emit final state
    scan_kernel<<<2048 / 256, 256, 0, stream>>>(up, dt, Avec, xlast);

    // 4. GEMM2: y[m, o] = sum_s x[m,s] * C[s,o] + D[o]
    dim3 g2(O_DIM / BN, M_ROWS / BM);
    gemm64<false, true><<<g2, 256, 0, stream>>>(up, Cmat, y, M_ROWS, O_DIM, S_DIM,
                                                nullptr, nullptr, Dvec);
}

// Round 2
// 98.638 us; speedup vs baseline: 3.3152x; 3.3152x over previous
//
#include <hip/hip_runtime.h>
#include <math.h>

#define I_DIM 1024
#define S_DIM 512
#define O_DIM 1024
#define T_DIM 2048
#define B_SZ 4
#define M_ROWS (B_SZ * T_DIM)   // 8192
#define EPSF 1e-6f

// scan chunking
#define CL 64
#define NCH 32   // NCH*CL == T_DIM

typedef __attribute__((ext_vector_type(8))) short bf16x8;
typedef __attribute__((ext_vector_type(4))) float f32x4;

__device__ __forceinline__ unsigned short f2bf(float f) {
    unsigned u = __float_as_uint(f);
    u += 0x7FFFu + ((u >> 16) & 1u);          // round-to-nearest-even
    return (unsigned short)(u >> 16);
}
__device__ __forceinline__ float bf2f(unsigned short h) {
    return __uint_as_float(((unsigned)h) << 16);
}

// async 16B global -> LDS (HW adds lane*16 to wave-uniform LDS base;
// our per-thread lds ptrs are exactly base + lane*16, so layout is linear)
__device__ __forceinline__ void load16_lds(const void* g, void* l) {
    __builtin_amdgcn_global_load_lds((const __attribute__((address_space(1))) void*)g,
                                     (__attribute__((address_space(3))) void*)l,
                                     16, 0, 0);
}

// ---------------------------------------------------------------------------
// RMSNorm + bf16 cast: out[row, i] = bf16( u[row,i] * rsqrt(mean(u^2)+eps) * nw[i] )
// one block (256 thr) per row of 1024 floats
// ---------------------------------------------------------------------------
__global__ __launch_bounds__(256)
void rmsnorm_bf16(const float* __restrict__ u, const float* __restrict__ nw,
                  unsigned short* __restrict__ out) {
    const int row = blockIdx.x;
    const int t = threadIdx.x;
    float4 v = ((const float4*)(u + (size_t)row * I_DIM))[t];
    float ss = v.x * v.x + v.y * v.y + v.z * v.z + v.w * v.w;
    #pragma unroll
    for (int off = 32; off > 0; off >>= 1) ss += __shfl_down(ss, off, 64);
    __shared__ float red[4];
    if ((t & 63) == 0) red[t >> 6] = ss;
    __syncthreads();
    if (t == 0) red[0] = rsqrtf((red[0] + red[1] + red[2] + red[3]) * (1.0f / I_DIM) + EPSF);
    __syncthreads();
    const float rs = red[0];
    float4 w = ((const float4*)nw)[t];
    ushort4 o;
    o.x = f2bf(v.x * rs * w.x);
    o.y = f2bf(v.y * rs * w.y);
    o.z = f2bf(v.z * rs * w.z);
    o.w = f2bf(v.w * rs * w.w);
    ((ushort4*)(out + (size_t)row * I_DIM))[t] = o;
}

// ---------------------------------------------------------------------------
// fp32 [R, Cc] -> bf16 transposed [Cc, R]
// ---------------------------------------------------------------------------
__global__ __launch_bounds__(256)
void transpose_f32_to_bf16(const float* __restrict__ in, unsigned short* __restrict__ out,
                           int R, int Cc) {
    __shared__ float tile[32][33];
    const int bx = blockIdx.x * 32, by = blockIdx.y * 32;
    const int tx = threadIdx.x & 31, ty = threadIdx.x >> 5;
    #pragma unroll
    for (int i = ty; i < 32; i += 8) tile[i][tx] = in[(size_t)(by + i) * Cc + bx + tx];
    __syncthreads();
    #pragma unroll
    for (int i = ty; i < 32; i += 8) out[(size_t)(bx + i) * R + by + tx] = f2bf(tile[tx][i]);
}

// ---------------------------------------------------------------------------
// bf16 MFMA GEMM, m97 structure: 128x128 tile, BK=32, 4 waves (each 64x64),
// 16x16x32 MFMA, global_load_lds width-16 staging, Bt pre-transposed [N, ldb].
// kmask lets GEMM2 reuse the same 512-row Ct for K=1024 (hi|lo split of A).
// ---------------------------------------------------------------------------
template<bool BIAS>
__global__ __launch_bounds__(256)
void mfma_gemm(const unsigned short* __restrict__ A, const unsigned short* __restrict__ Bt,
               float* __restrict__ Cout, int M, int N, int K, int ldb, int kmask,
               const float* __restrict__ bias) {
    __shared__ unsigned short As[128 * 32];
    __shared__ unsigned short Bs[128 * 32];
    const int t = threadIdx.x;
    const int m0 = blockIdx.y * 128, n0 = blockIdx.x * 128;
    const int ldr = t >> 2;          // 0..63: row within 64-row half-tile
    const int lc8 = (t & 3) * 8;     // 0/8/16/24: k-offset (8 bf16 = 16B)
    const int wid = t >> 6, lane = t & 63;
    const int wm = (wid >> 1) * 64, wn = (wid & 1) * 64;
    const int lr = lane & 15, kg = lane >> 4;

    f32x4 acc[4][4];
    #pragma unroll
    for (int i = 0; i < 4; ++i)
        #pragma unroll
        for (int j = 0; j < 4; ++j) acc[i][j] = (f32x4){0.f, 0.f, 0.f, 0.f};

    const size_t arow = (size_t)(m0 + ldr) * K + lc8;
    const size_t brow = (size_t)(n0 + ldr) * ldb + lc8;

    for (int k0 = 0; k0 < K; k0 += 32) {
        const int kb = k0 & kmask;
        load16_lds(A + arow + k0, &As[t * 8]);
        load16_lds(A + arow + (size_t)64 * K + k0, &As[2048 + t * 8]);
        load16_lds(Bt + brow + kb, &Bs[t * 8]);
        load16_lds(Bt + brow + (size_t)64 * ldb + kb, &Bs[2048 + t * 8]);
        __syncthreads();   // compiler drains vmcnt(0) here -> LDS tiles ready

        bf16x8 af[4], bfr[4];
        #pragma unroll
        for (int m = 0; m < 4; ++m)
            af[m] = *(const bf16x8*)&As[(wm + m * 16 + lr) * 32 + kg * 8];
        #pragma unroll
        for (int n = 0; n < 4; ++n)
            bfr[n] = *(const bf16x8*)&Bs[(wn + n * 16 + lr) * 32 + kg * 8];
        #pragma unroll
        for (int m = 0; m < 4; ++m)
            #pragma unroll
            for (int n = 0; n < 4; ++n)
                acc[m][n] = __builtin_amdgcn_mfma_f32_16x16x32_bf16(af[m], bfr[n], acc[m][n], 0, 0, 0);
        __syncthreads();   // protect LDS from next iteration's staging
    }

    // C/D layout: col = lane&15, row = (lane>>4)*4 + reg  [m89/m91 verified]
    #pragma unroll
    for (int m = 0; m < 4; ++m) {
        const int row = m0 + wm + m * 16 + kg * 4;
        #pragma unroll
        for (int n = 0; n < 4; ++n) {
            const int col = n0 + wn + n * 16 + lr;
            const float b = BIAS ? bias[col] : 0.0f;
            #pragma unroll
            for (int j = 0; j < 4; ++j)
                Cout[(size_t)(row + j) * N + col] = acc[m][n][j] + b;
        }
    }
}

// ---------------------------------------------------------------------------
// Chunked parallel linear scan:  x_t = a*x_{t-1} + dts*up_t
// pass1: per-chunk local scans (in place), emit chunk-final values
// pass2: sequential prefix over NCH chunks -> carry per chunk
// pass3: x_t = local_t + a^{tl+1}*carry; emit bf16 hi/lo split + final state
// ---------------------------------------------------------------------------
__global__ __launch_bounds__(256)
void scan_local(float* __restrict__ up, const float* __restrict__ dt,
                const float* __restrict__ Avec, float* __restrict__ chlast) {
    const int gid = blockIdx.x * 256 + threadIdx.x;      // 0 .. B*NCH*S-1
    const int s = gid & (S_DIM - 1);
    const int c = (gid >> 9) & (NCH - 1);
    const int b = gid >> 14;
    const float dts = 1.0f / (1.0f + expf(-dt[s]));
    const float a = expf(-dts * fabsf(Avec[s]));
    const size_t base = ((size_t)(b * T_DIM + c * CL)) * S_DIM + s;
    float x = 0.0f;
    for (int tl = 0; tl < CL; tl += 4) {
        float v0 = up[base + (size_t)(tl + 0) * S_DIM];
        float v1 = up[base + (size_t)(tl + 1) * S_DIM];
        float v2 = up[base + (size_t)(tl + 2) * S_DIM];
        float v3 = up[base + (size_t)(tl + 3) * S_DIM];
        x = fmaf(a, x, dts * v0); up[base + (size_t)(tl + 0) * S_DIM] = x;
        x = fmaf(a, x, dts * v1); up[base + (size_t)(tl + 1) * S_DIM] = x;
        x = fmaf(a, x, dts * v2); up[base + (size_t)(tl + 2) * S_DIM] = x;
        x = fmaf(a, x, dts * v3); up[base + (size_t)(tl + 3) * S_DIM] = x;
    }
    chlast[(size_t)(b * NCH + c) * S_DIM + s] = x;
}

__global__ __launch_bounds__(256)
void scan_carry(const float* __restrict__ chlast, const float* __restrict__ dt,
                const float* __restrict__ Avec, float* __restrict__ carry) {
    const int gid = blockIdx.x * 256 + threadIdx.x;      // 0..2047
    const int s = gid & (S_DIM - 1);
    const int b = gid >> 9;
    const float dts = 1.0f / (1.0f + expf(-dt[s]));
    const float aCL = expf(-dts * fabsf(Avec[s]) * (float)CL);
    float cy = 0.0f;
    for (int c = 0; c < NCH; ++c) {
        carry[(size_t)(b * NCH + c) * S_DIM + s] = cy;
        cy = fmaf(aCL, cy, chlast[(size_t)(b * NCH + c) * S_DIM + s]);
    }
}

__global__ __launch_bounds__(256)
void scan_combine(const float* __restrict__ up, const float* __restrict__ carry,
                  const float* __restrict__ dt, const float* __restrict__ Avec,
                  unsigned short* __restrict__ xhilo, float* __restrict__ xlast) {
    const int gid = blockIdx.x * 256 + threadIdx.x;
    const int s = gid & (S_DIM - 1);
    const int c = (gid >> 9) & (NCH - 1);
    const int b = gid >> 14;
    const float dts = 1.0f / (1.0f + expf(-dt[s]));
    const float a = expf(-dts * fabsf(Avec[s]));
    const float cy = carry[(size_t)(b * NCH + c) * S_DIM + s];
    const size_t rbase = ((size_t)(b * T_DIM + c * CL)) * S_DIM + s;
    const size_t wrow = (size_t)(b * T_DIM + c * CL);
    float pf = a;
    float xg = 0.0f;
    for (int tl = 0; tl < CL; ++tl) {
        xg = fmaf(pf, cy, up[rbase + (size_t)tl * S_DIM]);
        pf *= a;
        const unsigned short hi = f2bf(xg);
        const unsigned short lo = f2bf(xg - bf2f(hi));
        xhilo[(wrow + tl) * (2 * S_DIM) + s] = hi;
        xhilo[(wrow + tl) * (2 * S_DIM) + S_DIM + s] = lo;
    }
    if (c == NCH - 1) xlast[b * S_DIM + s] = xg;
}

// ---------------------------------------------------------------------------
extern "C" void kernel_launch(void* const* d_in, const int* in_sizes, int n_in,
                              void* d_out, int out_size, void* d_ws, size_t ws_size,
                              hipStream_t stream) {
    const float* u    = (const float*)d_in[0];   // [B,T,I]
    const float* dt   = (const float*)d_in[1];   // [S]
    const float* Avec = (const float*)d_in[2];   // [S]
    const float* Bmat = (const float*)d_in[3];   // [I,S]
    const float* Cmat = (const float*)d_in[4];   // [S,O]
    const float* Dvec = (const float*)d_in[5];   // [O]
    const float* nw   = (const float*)d_in[6];   // [I]

    float* y     = (float*)d_out;                      // [B,T,O] fp32
    float* xlast = y + (size_t)M_ROWS * O_DIM;         // [B,S]   fp32

    // workspace layout (≈34.5 MB)
    char* w = (char*)d_ws;
    unsigned short* u_bf   = (unsigned short*)(w);                 // [8192,1024] bf16 (reused as xhilo)
    float*          up     = (float*)(w + 16777216);               // [8192,512]  fp32
    unsigned short* Btb    = (unsigned short*)(w + 33554432);      // [512,1024]  bf16  B^T
    unsigned short* Ctb    = (unsigned short*)(w + 34603008);      // [1024,512]  bf16  C^T
    float*          chlast = (float*)(w + 35651584);               // [B,NCH,S]
    float*          carry  = (float*)(w + 35913728);               // [B,NCH,S]

    // 1. fused RMSNorm -> bf16
    rmsnorm_bf16<<<M_ROWS, 256, 0, stream>>>(u, nw, u_bf);

    // 2. transpose-convert weights
    dim3 gtB(S_DIM / 32, I_DIM / 32);
    transpose_f32_to_bf16<<<gtB, 256, 0, stream>>>(Bmat, Btb, I_DIM, S_DIM);
    dim3 gtC(O_DIM / 32, S_DIM / 32);
    transpose_f32_to_bf16<<<gtC, 256, 0, stream>>>(Cmat, Ctb, S_DIM, O_DIM);

    // 3. GEMM1: up = u_bf @ B   (M=8192, N=512, K=1024)
    dim3 g1(S_DIM / 128, M_ROWS / 128);
    mfma_gemm<false><<<g1, 256, 0, stream>>>(u_bf, Btb, up, M_ROWS, S_DIM, I_DIM,
                                             I_DIM, I_DIM - 1, nullptr);

    // 4. chunked linear scan; emits bf16 hi/lo split x into xhilo (= u_bf region)
    unsigned short* xhilo = u_bf;
    scan_local<<<(B_SZ * NCH * S_DIM) / 256, 256, 0, stream>>>(up, dt, Avec, chlast);
    scan_carry<<<(B_SZ * S_DIM) / 256, 256, 0, stream>>>(chlast, dt, Avec, carry);
    scan_combine<<<(B_SZ * NCH * S_DIM) / 256, 256, 0, stream>>>(up, carry, dt, Avec,
                                                                 xhilo, xlast);

    // 5. GEMM2: y = (xhi + xlo) @ C + D   (M=8192, N=1024, K=2*512 via kmask)
    dim3 g2(O_DIM / 128, M_ROWS / 128);
    mfma_gemm<true><<<g2, 256, 0, stream>>>(xhilo, Ctb, y, M_ROWS, O_DIM, 2 * S_DIM,
                                            S_DIM, S_DIM - 1, Dvec);
}

// Round 3
// 79.925 us; speedup vs baseline: 4.0913x; 1.2341x over previous
//
#include <hip/hip_runtime.h>
#include <math.h>

#define I_DIM 1024
#define S_DIM 512
#define O_DIM 1024
#define T_DIM 2048
#define B_SZ 4
#define M_ROWS (B_SZ * T_DIM)   // 8192
#define EPSF 1e-6f

// scan chunking
#define CL 128
#define NCH 16   // NCH*CL == T_DIM

typedef _Float16 f16;
typedef __attribute__((ext_vector_type(8))) _Float16 f16x8;
typedef __attribute__((ext_vector_type(2))) _Float16 f16x2;
typedef __attribute__((ext_vector_type(4))) float f32x4;

__device__ __forceinline__ unsigned short f2h_bits(float f) {
    _Float16 h = (_Float16)f;
    return __builtin_bit_cast(unsigned short, h);
}

// async 16B global -> LDS (wave-uniform LDS base + lane*16; our per-thread
// dest = base + tid*16 matches the HW layout exactly)
__device__ __forceinline__ void load16_lds(const void* g, void* l) {
    __builtin_amdgcn_global_load_lds((const __attribute__((address_space(1))) void*)g,
                                     (__attribute__((address_space(3))) void*)l,
                                     16, 0, 0);
}

// ---------------------------------------------------------------------------
// RMSNorm + fp16 cast: out[row,i] = f16( u[row,i] * rsqrt(mean(u^2)+eps) * nw[i] )
// ---------------------------------------------------------------------------
__global__ __launch_bounds__(256)
void rmsnorm_f16(const float* __restrict__ u, const float* __restrict__ nw,
                 unsigned short* __restrict__ out) {
    const int row = blockIdx.x;
    const int t = threadIdx.x;
    float4 v = ((const float4*)(u + (size_t)row * I_DIM))[t];
    float ss = v.x * v.x + v.y * v.y + v.z * v.z + v.w * v.w;
    #pragma unroll
    for (int off = 32; off > 0; off >>= 1) ss += __shfl_down(ss, off, 64);
    __shared__ float red[4];
    if ((t & 63) == 0) red[t >> 6] = ss;
    __syncthreads();
    if (t == 0) red[0] = rsqrtf((red[0] + red[1] + red[2] + red[3]) * (1.0f / I_DIM) + EPSF);
    __syncthreads();
    const float rs = red[0];
    float4 w = ((const float4*)nw)[t];
    ushort4 o;
    o.x = f2h_bits(v.x * rs * w.x);
    o.y = f2h_bits(v.y * rs * w.y);
    o.z = f2h_bits(v.z * rs * w.z);
    o.w = f2h_bits(v.w * rs * w.w);
    ((ushort4*)(out + (size_t)row * I_DIM))[t] = o;
}

// ---------------------------------------------------------------------------
// fp32 [R, Cc] -> fp16 transposed [Cc, R]
// ---------------------------------------------------------------------------
__global__ __launch_bounds__(256)
void transpose_f32_to_f16(const float* __restrict__ in, unsigned short* __restrict__ out,
                          int R, int Cc) {
    __shared__ float tile[32][33];
    const int bx = blockIdx.x * 32, by = blockIdx.y * 32;
    const int tx = threadIdx.x & 31, ty = threadIdx.x >> 5;
    #pragma unroll
    for (int i = ty; i < 32; i += 8) tile[i][tx] = in[(size_t)(by + i) * Cc + bx + tx];
    __syncthreads();
    #pragma unroll
    for (int i = ty; i < 32; i += 8) out[(size_t)(bx + i) * R + by + tx] = f2h_bits(tile[tx][i]);
}

// ---------------------------------------------------------------------------
// fp16 MFMA GEMM (m97 structure): 128x128 tile, BK=32, 4 waves (64x64 each),
// 16x16x32_f16 MFMA, width-16 global_load_lds staging, Bt pre-transposed
// [N, ldb]. XCD-aware block swizzle keeps blocks sharing an A-panel on one XCD.
// ---------------------------------------------------------------------------
template<bool BIAS, typename OUT>
__global__ __launch_bounds__(256)
void mfma_gemm_f16(const f16* __restrict__ A, const f16* __restrict__ Bt,
                   OUT* __restrict__ Cout, int M, int N, int K, int ldb,
                   const float* __restrict__ bias) {
    __shared__ f16 As[128 * 32];
    __shared__ f16 Bs[128 * 32];
    const int t = threadIdx.x;

    // XCD swizzle (nwg % 8 == 0 for both our grids)
    int bid = blockIdx.y * gridDim.x + blockIdx.x;
    const int nwg = gridDim.x * gridDim.y;
    const int cpx = nwg >> 3;
    bid = (bid & 7) * cpx + (bid >> 3);
    const int n0 = (bid % gridDim.x) * 128;
    const int m0 = (bid / gridDim.x) * 128;

    const int ldr = t >> 2;          // 0..63: row within half-tile
    const int lc8 = (t & 3) * 8;     // k-offset (8 halfs = 16B)
    const int wid = t >> 6, lane = t & 63;
    const int wm = (wid >> 1) * 64, wn = (wid & 1) * 64;
    const int lr = lane & 15, kg = lane >> 4;

    f32x4 acc[4][4];
    #pragma unroll
    for (int i = 0; i < 4; ++i)
        #pragma unroll
        for (int j = 0; j < 4; ++j) acc[i][j] = (f32x4){0.f, 0.f, 0.f, 0.f};

    const size_t arow = (size_t)(m0 + ldr) * K + lc8;
    const size_t brow = (size_t)(n0 + ldr) * ldb + lc8;

    for (int k0 = 0; k0 < K; k0 += 32) {
        load16_lds(A + arow + k0, &As[t * 8]);
        load16_lds(A + arow + (size_t)64 * K + k0, &As[2048 + t * 8]);
        load16_lds(Bt + brow + k0, &Bs[t * 8]);
        load16_lds(Bt + brow + (size_t)64 * ldb + k0, &Bs[2048 + t * 8]);
        __syncthreads();   // compiler drains vmcnt(0) before barrier

        f16x8 af[4], bfr[4];
        #pragma unroll
        for (int m = 0; m < 4; ++m)
            af[m] = *(const f16x8*)&As[(wm + m * 16 + lr) * 32 + kg * 8];
        #pragma unroll
        for (int n = 0; n < 4; ++n)
            bfr[n] = *(const f16x8*)&Bs[(wn + n * 16 + lr) * 32 + kg * 8];
        #pragma unroll
        for (int m = 0; m < 4; ++m)
            #pragma unroll
            for (int n = 0; n < 4; ++n)
                acc[m][n] = __builtin_amdgcn_mfma_f32_16x16x32_f16(af[m], bfr[n], acc[m][n], 0, 0, 0);
        __syncthreads();
    }

    // C/D layout: col = lane&15, row = (lane>>4)*4 + reg  [m89/m91 verified]
    #pragma unroll
    for (int m = 0; m < 4; ++m) {
        const int row = m0 + wm + m * 16 + kg * 4;
        #pragma unroll
        for (int n = 0; n < 4; ++n) {
            const int col = n0 + wn + n * 16 + lr;
            const float b = BIAS ? bias[col] : 0.0f;
            #pragma unroll
            for (int j = 0; j < 4; ++j) {
                if constexpr (sizeof(OUT) == 4)
                    Cout[(size_t)(row + j) * N + col] = (OUT)(acc[m][n][j] + b);
                else
                    Cout[(size_t)(row + j) * N + col] = (OUT)(_Float16)acc[m][n][j];
            }
        }
    }
}

// ---------------------------------------------------------------------------
// Chunked parallel linear scan over fp16 up:  x_t = a*x_{t-1} + dts*up_t
// Each thread owns 2 adjacent s-channels (uint = 2 halfs per load).
// pass1: chunk-final local value only (no intermediate writes)
// pass2: sequential carry over NCH chunks
// pass3: re-scan with carry init, emit fp16 x + final state
// ---------------------------------------------------------------------------
__global__ __launch_bounds__(256)
void scan_chunk_final(const f16* __restrict__ up, const float* __restrict__ dt,
                      const float* __restrict__ Avec, float* __restrict__ chlast) {
    const int gid = blockIdx.x * 256 + threadIdx.x;   // 0 .. B*NCH*S/2-1
    const int s2 = gid & 255;
    const int c = (gid >> 8) & (NCH - 1);
    const int b = gid >> 12;
    const int s0 = s2 * 2;
    const float dts0 = 1.0f / (1.0f + expf(-dt[s0]));
    const float dts1 = 1.0f / (1.0f + expf(-dt[s0 + 1]));
    const float a0 = expf(-dts0 * fabsf(Avec[s0]));
    const float a1 = expf(-dts1 * fabsf(Avec[s0 + 1]));
    const unsigned* up32 = (const unsigned*)up;
    const size_t base = (size_t)(b * T_DIM + c * CL) * 256 + s2;
    float x0 = 0.f, x1 = 0.f;
    for (int tl = 0; tl < CL; tl += 4) {
        unsigned v[4];
        #pragma unroll
        for (int j = 0; j < 4; ++j) v[j] = up32[base + (size_t)(tl + j) * 256];
        #pragma unroll
        for (int j = 0; j < 4; ++j) {
            f16x2 h = __builtin_bit_cast(f16x2, v[j]);
            x0 = fmaf(a0, x0, dts0 * (float)h.x);
            x1 = fmaf(a1, x1, dts1 * (float)h.y);
        }
    }
    ((float2*)chlast)[(size_t)(b * NCH + c) * 256 + s2] = make_float2(x0, x1);
}

__global__ __launch_bounds__(256)
void scan_carry(const float* __restrict__ chlast, const float* __restrict__ dt,
                const float* __restrict__ Avec, float* __restrict__ carry) {
    const int gid = blockIdx.x * 256 + threadIdx.x;   // 0..2047
    const int s = gid & (S_DIM - 1);
    const int b = gid >> 9;
    const float dts = 1.0f / (1.0f + expf(-dt[s]));
    const float aCL = expf(-dts * fabsf(Avec[s]) * (float)CL);
    float cy = 0.0f;
    for (int c = 0; c < NCH; ++c) {
        carry[(size_t)(b * NCH + c) * S_DIM + s] = cy;
        cy = fmaf(aCL, cy, chlast[(size_t)(b * NCH + c) * S_DIM + s]);
    }
}

__global__ __launch_bounds__(256)
void scan_apply(const f16* __restrict__ up, const float* __restrict__ carry,
                const float* __restrict__ dt, const float* __restrict__ Avec,
                unsigned* __restrict__ x32, float* __restrict__ xlast) {
    const int gid = blockIdx.x * 256 + threadIdx.x;
    const int s2 = gid & 255;
    const int c = (gid >> 8) & (NCH - 1);
    const int b = gid >> 12;
    const int s0 = s2 * 2;
    const float dts0 = 1.0f / (1.0f + expf(-dt[s0]));
    const float dts1 = 1.0f / (1.0f + expf(-dt[s0 + 1]));
    const float a0 = expf(-dts0 * fabsf(Avec[s0]));
    const float a1 = expf(-dts1 * fabsf(Avec[s0 + 1]));
    const float2 cy = ((const float2*)carry)[(size_t)(b * NCH + c) * 256 + s2];
    const unsigned* up32 = (const unsigned*)up;
    const size_t base = (size_t)(b * T_DIM + c * CL) * 256 + s2;
    float x0 = cy.x, x1 = cy.y;
    for (int tl = 0; tl < CL; tl += 4) {
        unsigned v[4];
        #pragma unroll
        for (int j = 0; j < 4; ++j) v[j] = up32[base + (size_t)(tl + j) * 256];
        #pragma unroll
        for (int j = 0; j < 4; ++j) {
            f16x2 h = __builtin_bit_cast(f16x2, v[j]);
            x0 = fmaf(a0, x0, dts0 * (float)h.x);
            x1 = fmaf(a1, x1, dts1 * (float)h.y);
            f16x2 o; o.x = (_Float16)x0; o.y = (_Float16)x1;
            v[j] = __builtin_bit_cast(unsigned, o);
        }
        #pragma unroll
        for (int j = 0; j < 4; ++j) x32[base + (size_t)(tl + j) * 256] = v[j];
    }
    if (c == NCH - 1) ((float2*)xlast)[b * 256 + s2] = make_float2(x0, x1);
}

// ---------------------------------------------------------------------------
extern "C" void kernel_launch(void* const* d_in, const int* in_sizes, int n_in,
                              void* d_out, int out_size, void* d_ws, size_t ws_size,
                              hipStream_t stream) {
    const float* u    = (const float*)d_in[0];   // [B,T,I]
    const float* dt   = (const float*)d_in[1];   // [S]
    const float* Avec = (const float*)d_in[2];   // [S]
    const float* Bmat = (const float*)d_in[3];   // [I,S]
    const float* Cmat = (const float*)d_in[4];   // [S,O]
    const float* Dvec = (const float*)d_in[5];   // [O]
    const float* nw   = (const float*)d_in[6];   // [I]

    float* y     = (float*)d_out;                      // [B,T,O] fp32
    float* xlast = y + (size_t)M_ROWS * O_DIM;         // [B,S]   fp32

    // workspace layout (~36 MB)
    char* w = (char*)d_ws;
    unsigned short* u16    = (unsigned short*)(w);               // [8192,1024] f16
    f16*            up16   = (f16*)(w + 16777216);               // [8192,512]  f16
    f16*            x16    = (f16*)(w + 25165824);               // [8192,512]  f16
    unsigned short* Bt16   = (unsigned short*)(w + 33554432);    // [512,1024]  f16 B^T
    unsigned short* Ct16   = (unsigned short*)(w + 34603008);    // [1024,512]  f16 C^T
    float*          chlast = (float*)(w + 35651584);             // [B,NCH,S]
    float*          carry  = (float*)(w + 35782656);             // [B,NCH,S]

    // 1. fused RMSNorm -> fp16
    rmsnorm_f16<<<M_ROWS, 256, 0, stream>>>(u, nw, u16);

    // 2. transpose-convert weights
    dim3 gtB(S_DIM / 32, I_DIM / 32);
    transpose_f32_to_f16<<<gtB, 256, 0, stream>>>(Bmat, Bt16, I_DIM, S_DIM);
    dim3 gtC(O_DIM / 32, S_DIM / 32);
    transpose_f32_to_f16<<<gtC, 256, 0, stream>>>(Cmat, Ct16, S_DIM, O_DIM);

    // 3. GEMM1: up16 = u16 @ B   (M=8192, N=512, K=1024), fp16 out
    dim3 g1(S_DIM / 128, M_ROWS / 128);
    mfma_gemm_f16<false, f16><<<g1, 256, 0, stream>>>((const f16*)u16, (const f16*)Bt16,
                                                      up16, M_ROWS, S_DIM, I_DIM, I_DIM,
                                                      nullptr);

    // 4. chunked linear scan (fp32 accum), emit fp16 x + final state
    scan_chunk_final<<<(B_SZ * NCH * S_DIM / 2) / 256, 256, 0, stream>>>(up16, dt, Avec, chlast);
    scan_carry<<<(B_SZ * S_DIM) / 256, 256, 0, stream>>>(chlast, dt, Avec, carry);
    scan_apply<<<(B_SZ * NCH * S_DIM / 2) / 256, 256, 0, stream>>>(up16, carry, dt, Avec,
                                                                   (unsigned*)x16, xlast);

    // 5. GEMM2: y = x16 @ C + D   (M=8192, N=1024, K=512), fp32 out
    dim3 g2(O_DIM / 128, M_ROWS / 128);
    mfma_gemm_f16<true, float><<<g2, 256, 0, stream>>>(x16, (const f16*)Ct16, y,
                                                       M_ROWS, O_DIM, S_DIM, S_DIM, Dvec);
}

// Round 4
// 70.860 us; speedup vs baseline: 4.6147x; 1.1279x over previous
//
#include <hip/hip_runtime.h>
#include <math.h>

#define I_DIM 1024
#define S_DIM 512
#define O_DIM 1024
#define T_DIM 2048
#define B_SZ 4
#define M_ROWS (B_SZ * T_DIM)   // 8192
#define EPSF 1e-6f

// scan chunking
#define CL 64
#define NCH 32   // NCH*CL == T_DIM

typedef _Float16 f16;
typedef __attribute__((ext_vector_type(8))) _Float16 f16x8;
typedef __attribute__((ext_vector_type(2))) _Float16 f16x2;
typedef __attribute__((ext_vector_type(4))) float f32x4;

__device__ __forceinline__ unsigned short f2h_bits(float f) {
    _Float16 h = (_Float16)f;
    return __builtin_bit_cast(unsigned short, h);
}

// async 16B global -> LDS (wave-uniform LDS base + lane*16; per-thread dest
// = base + tid*16 matches HW layout exactly)
__device__ __forceinline__ void load16_lds(const void* g, void* l) {
    __builtin_amdgcn_global_load_lds((const __attribute__((address_space(1))) void*)g,
                                     (__attribute__((address_space(3))) void*)l,
                                     16, 0, 0);
}

// ---------------------------------------------------------------------------
// prep: fused RMSNorm->fp16  +  B^T (scaled by dts)  +  C^T, one launch.
//   blocks [0, 8192)            : rmsnorm rows
//   blocks [8192, 8704)         : B transpose tiles (16 s-blocks x 32 i-blocks)
//   blocks [8704, 9216)         : C transpose tiles (32 o-blocks x 16 s-blocks)
// ---------------------------------------------------------------------------
__global__ __launch_bounds__(256)
void prep(const float* __restrict__ u, const float* __restrict__ nw,
          unsigned short* __restrict__ u16,
          const float* __restrict__ Bmat, const float* __restrict__ dt,
          unsigned short* __restrict__ Bt16,
          const float* __restrict__ Cmat, unsigned short* __restrict__ Ct16) {
    __shared__ float tile[32][33];
    const int t = threadIdx.x;
    const int bx = blockIdx.x;

    if (bx < M_ROWS) {
        // ---- RMSNorm + fp16 cast ----
        float4 v = ((const float4*)(u + (size_t)bx * I_DIM))[t];
        float ss = v.x * v.x + v.y * v.y + v.z * v.z + v.w * v.w;
        #pragma unroll
        for (int off = 32; off > 0; off >>= 1) ss += __shfl_down(ss, off, 64);
        if ((t & 63) == 0) tile[0][t >> 6] = ss;
        __syncthreads();
        if (t == 0)
            tile[0][0] = rsqrtf((tile[0][0] + tile[0][1] + tile[0][2] + tile[0][3])
                                * (1.0f / I_DIM) + EPSF);
        __syncthreads();
        const float rs = tile[0][0];
        float4 w = ((const float4*)nw)[t];
        ushort4 o;
        o.x = f2h_bits(v.x * rs * w.x);
        o.y = f2h_bits(v.y * rs * w.y);
        o.z = f2h_bits(v.z * rs * w.z);
        o.w = f2h_bits(v.w * rs * w.w);
        ((ushort4*)(u16 + (size_t)bx * I_DIM))[t] = o;
    } else if (bx < M_ROWS + 512) {
        // ---- B^T with dts fold: Bt16[s, i] = f16(B[i, s] * sigmoid(dt[s])) ----
        const int tb = bx - M_ROWS;
        const int bs = (tb & 15) * 32;   // s block
        const int bi = (tb >> 4) * 32;   // i block
        const int tx = t & 31, ty = t >> 5;
        #pragma unroll
        for (int i = ty; i < 32; i += 8)
            tile[i][tx] = Bmat[(size_t)(bi + i) * S_DIM + bs + tx];
        __syncthreads();
        #pragma unroll
        for (int i = ty; i < 32; i += 8) {
            const int s = bs + i;
            const float dts = 1.0f / (1.0f + expf(-dt[s]));
            Bt16[(size_t)s * I_DIM + bi + tx] = f2h_bits(tile[tx][i] * dts);
        }
    } else {
        // ---- C^T: Ct16[o, s] = f16(C[s, o]) ----
        const int tb = bx - M_ROWS - 512;
        const int bo = (tb & 31) * 32;   // o block
        const int bs = (tb >> 5) * 32;   // s block
        const int tx = t & 31, ty = t >> 5;
        #pragma unroll
        for (int i = ty; i < 32; i += 8)
            tile[i][tx] = Cmat[(size_t)(bs + i) * O_DIM + bo + tx];
        __syncthreads();
        #pragma unroll
        for (int i = ty; i < 32; i += 8)
            Ct16[(size_t)(bo + i) * S_DIM + bs + tx] = f2h_bits(tile[tx][i]);
    }
}

// ---------------------------------------------------------------------------
// fp16 MFMA GEMM, 128x128 tile, BK=32, 4 waves, 2-phase double-buffered LDS:
// issue next-tile global_load_lds BEFORE computing current tile, wait with
// counted vmcnt(4) (next tile's loads stay in flight), raw s_barrier pair.
// ---------------------------------------------------------------------------
template<bool BIAS, typename OUT>
__global__ __launch_bounds__(256)
void mfma_gemm_f16(const f16* __restrict__ A, const f16* __restrict__ Bt,
                   OUT* __restrict__ Cout, int M, int N, int K, int ldb,
                   const float* __restrict__ bias) {
    __shared__ f16 As[2][128 * 32];
    __shared__ f16 Bs[2][128 * 32];
    const int t = threadIdx.x;

    // XCD swizzle (nwg % 8 == 0 for both grids)
    int bid = blockIdx.y * gridDim.x + blockIdx.x;
    const int nwg = gridDim.x * gridDim.y;
    const int cpx = nwg >> 3;
    bid = (bid & 7) * cpx + (bid >> 3);
    const int n0 = (bid % gridDim.x) * 128;
    const int m0 = (bid / gridDim.x) * 128;

    const int ldr = t >> 2;          // 0..63: row within half-tile
    const int lc8 = (t & 3) * 8;     // k-offset (8 halfs = 16B)
    const int wid = t >> 6, lane = t & 63;
    const int wm = (wid >> 1) * 64, wn = (wid & 1) * 64;
    const int lr = lane & 15, kg = lane >> 4;

    f32x4 acc[4][4];
    #pragma unroll
    for (int i = 0; i < 4; ++i)
        #pragma unroll
        for (int j = 0; j < 4; ++j) acc[i][j] = (f32x4){0.f, 0.f, 0.f, 0.f};

    const size_t arow = (size_t)(m0 + ldr) * K + lc8;
    const size_t brow = (size_t)(n0 + ldr) * ldb + lc8;

    auto stage = [&](int k0, int bsel) {
        load16_lds(A + arow + k0, &As[bsel][t * 8]);
        load16_lds(A + arow + (size_t)64 * K + k0, &As[bsel][2048 + t * 8]);
        load16_lds(Bt + brow + k0, &Bs[bsel][t * 8]);
        load16_lds(Bt + brow + (size_t)64 * ldb + k0, &Bs[bsel][2048 + t * 8]);
    };

    const int nk = K >> 5;
    stage(0, 0);
    for (int kt = 0; kt < nk; ++kt) {
        const int cur = kt & 1;
        if (kt + 1 < nk) {
            stage((kt + 1) << 5, cur ^ 1);   // prefetch next tile (stays in flight)
            asm volatile("s_waitcnt vmcnt(4)");   // my 4 current-tile loads done
        } else {
            asm volatile("s_waitcnt vmcnt(0)");
        }
        __builtin_amdgcn_s_barrier();        // all waves' current-tile loads done
        __builtin_amdgcn_sched_barrier(0);   // keep ds_reads below the barrier

        f16x8 af[4], bfr[4];
        #pragma unroll
        for (int m = 0; m < 4; ++m)
            af[m] = *(const f16x8*)&As[cur][(wm + m * 16 + lr) * 32 + kg * 8];
        #pragma unroll
        for (int n = 0; n < 4; ++n)
            bfr[n] = *(const f16x8*)&Bs[cur][(wn + n * 16 + lr) * 32 + kg * 8];
        #pragma unroll
        for (int m = 0; m < 4; ++m)
            #pragma unroll
            for (int n = 0; n < 4; ++n)
                acc[m][n] = __builtin_amdgcn_mfma_f32_16x16x32_f16(af[m], bfr[n], acc[m][n], 0, 0, 0);
        __builtin_amdgcn_s_barrier();        // reads of buf done before it's restaged
    }

    // C/D layout: col = lane&15, row = (lane>>4)*4 + reg
    #pragma unroll
    for (int m = 0; m < 4; ++m) {
        const int row = m0 + wm + m * 16 + kg * 4;
        #pragma unroll
        for (int n = 0; n < 4; ++n) {
            const int col = n0 + wn + n * 16 + lr;
            const float b = BIAS ? bias[col] : 0.0f;
            #pragma unroll
            for (int j = 0; j < 4; ++j) {
                if constexpr (sizeof(OUT) == 4)
                    Cout[(size_t)(row + j) * N + col] = (OUT)(acc[m][n][j] + b);
                else
                    Cout[(size_t)(row + j) * N + col] = (OUT)(_Float16)acc[m][n][j];
            }
        }
    }
}

// ---------------------------------------------------------------------------
// Chunked parallel linear scan (dts pre-folded into up):  x_t = a*x_{t-1} + v_t
// Thread owns 2 adjacent s-channels; whole chunk loaded to registers up-front
// (CL independent loads in flight -> one latency exposure).
// pass1: chunk-final local values
// pass2: apply — self-computed carry prefix (<=31 FMA over L2-hot chunk finals),
//        re-scan chunk, emit fp16 x + final state
// ---------------------------------------------------------------------------
__global__ __launch_bounds__(256)
void scan_chunk_final(const f16* __restrict__ up, const float* __restrict__ dt,
                      const float* __restrict__ Avec, float* __restrict__ chlast) {
    const int gid = blockIdx.x * 256 + threadIdx.x;   // 0 .. B*NCH*256-1
    const int s2 = gid & 255;
    const int c = (gid >> 8) & (NCH - 1);
    const int b = gid >> 13;
    const int s0 = s2 * 2;
    const float dts0 = 1.0f / (1.0f + expf(-dt[s0]));
    const float dts1 = 1.0f / (1.0f + expf(-dt[s0 + 1]));
    const float a0 = expf(-dts0 * fabsf(Avec[s0]));
    const float a1 = expf(-dts1 * fabsf(Avec[s0 + 1]));
    const unsigned* up32 = (const unsigned*)up;
    const size_t base = (size_t)(b * T_DIM + c * CL) * 256 + s2;

    unsigned v[CL];
    #pragma unroll
    for (int j = 0; j < CL; ++j) v[j] = up32[base + (size_t)j * 256];
    float x0 = 0.f, x1 = 0.f;
    #pragma unroll
    for (int j = 0; j < CL; ++j) {
        f16x2 h = __builtin_bit_cast(f16x2, v[j]);
        x0 = fmaf(a0, x0, (float)h.x);
        x1 = fmaf(a1, x1, (float)h.y);
    }
    ((float2*)chlast)[(size_t)(b * NCH + c) * 256 + s2] = make_float2(x0, x1);
}

__global__ __launch_bounds__(256)
void scan_apply(const f16* __restrict__ up, const float* __restrict__ chlast,
                const float* __restrict__ dt, const float* __restrict__ Avec,
                unsigned* __restrict__ x32, float* __restrict__ xlast) {
    const int gid = blockIdx.x * 256 + threadIdx.x;
    const int s2 = gid & 255;
    const int c = (gid >> 8) & (NCH - 1);
    const int b = gid >> 13;
    const int s0 = s2 * 2;
    const float dts0 = 1.0f / (1.0f + expf(-dt[s0]));
    const float dts1 = 1.0f / (1.0f + expf(-dt[s0 + 1]));
    const float ab0 = fabsf(Avec[s0]), ab1 = fabsf(Avec[s0 + 1]);
    const float a0 = expf(-dts0 * ab0);
    const float a1 = expf(-dts1 * ab1);
    const float aCL0 = expf(-dts0 * ab0 * (float)CL);
    const float aCL1 = expf(-dts1 * ab1 * (float)CL);

    // carry prefix over chunk finals 0..c-1 (c uniform per block)
    const float2* ch = (const float2*)chlast;
    float cy0 = 0.f, cy1 = 0.f;
    for (int j = 0; j < c; ++j) {
        float2 f = ch[(size_t)(b * NCH + j) * 256 + s2];
        cy0 = fmaf(aCL0, cy0, f.x);
        cy1 = fmaf(aCL1, cy1, f.y);
    }

    const unsigned* up32 = (const unsigned*)up;
    const size_t base = (size_t)(b * T_DIM + c * CL) * 256 + s2;
    unsigned v[CL];
    #pragma unroll
    for (int j = 0; j < CL; ++j) v[j] = up32[base + (size_t)j * 256];
    float x0 = cy0, x1 = cy1;
    #pragma unroll
    for (int j = 0; j < CL; ++j) {
        f16x2 h = __builtin_bit_cast(f16x2, v[j]);
        x0 = fmaf(a0, x0, (float)h.x);
        x1 = fmaf(a1, x1, (float)h.y);
        f16x2 o; o.x = (_Float16)x0; o.y = (_Float16)x1;
        v[j] = __builtin_bit_cast(unsigned, o);
    }
    #pragma unroll
    for (int j = 0; j < CL; ++j) x32[base + (size_t)j * 256] = v[j];
    if (c == NCH - 1) ((float2*)xlast)[b * 256 + s2] = make_float2(x0, x1);
}

// ---------------------------------------------------------------------------
extern "C" void kernel_launch(void* const* d_in, const int* in_sizes, int n_in,
                              void* d_out, int out_size, void* d_ws, size_t ws_size,
                              hipStream_t stream) {
    const float* u    = (const float*)d_in[0];   // [B,T,I]
    const float* dt   = (const float*)d_in[1];   // [S]
    const float* Avec = (const float*)d_in[2];   // [S]
    const float* Bmat = (const float*)d_in[3];   // [I,S]
    const float* Cmat = (const float*)d_in[4];   // [S,O]
    const float* Dvec = (const float*)d_in[5];   // [O]
    const float* nw   = (const float*)d_in[6];   // [I]

    float* y     = (float*)d_out;                      // [B,T,O] fp32
    float* xlast = y + (size_t)M_ROWS * O_DIM;         // [B,S]   fp32

    // workspace layout (~36 MB)
    char* w = (char*)d_ws;
    unsigned short* u16    = (unsigned short*)(w);               // [8192,1024] f16
    f16*            up16   = (f16*)(w + 16777216);               // [8192,512]  f16
    f16*            x16    = (f16*)(w + 25165824);               // [8192,512]  f16
    unsigned short* Bt16   = (unsigned short*)(w + 33554432);    // [512,1024]  f16 B^T (dts-scaled)
    unsigned short* Ct16   = (unsigned short*)(w + 34603008);    // [1024,512]  f16 C^T
    float*          chlast = (float*)(w + 35651584);             // [B,NCH,S] fp32 (256 KB)

    // 1. fused prep: rmsnorm->fp16 + B^T(dts) + C^T
    prep<<<M_ROWS + 512 + 512, 256, 0, stream>>>(u, nw, u16, Bmat, dt, Bt16, Cmat, Ct16);

    // 2. GEMM1: up16 = u16 @ (B*dts)   (M=8192, N=512, K=1024)
    dim3 g1(S_DIM / 128, M_ROWS / 128);
    mfma_gemm_f16<false, f16><<<g1, 256, 0, stream>>>((const f16*)u16, (const f16*)Bt16,
                                                      up16, M_ROWS, S_DIM, I_DIM, I_DIM,
                                                      nullptr);

    // 3. chunked linear scan (fp32 accum), emit fp16 x + final state
    scan_chunk_final<<<(B_SZ * NCH * 256) / 256, 256, 0, stream>>>(up16, dt, Avec, chlast);
    scan_apply<<<(B_SZ * NCH * 256) / 256, 256, 0, stream>>>(up16, chlast, dt, Avec,
                                                             (unsigned*)x16, xlast);

    // 4. GEMM2: y = x16 @ C + D   (M=8192, N=1024, K=512)
    dim3 g2(O_DIM / 128, M_ROWS / 128);
    mfma_gemm_f16<true, float><<<g2, 256, 0, stream>>>(x16, (const f16*)Ct16, y,
                                                       M_ROWS, O_DIM, S_DIM, S_DIM, Dvec);
}

// Round 5
// 65.074 us; speedup vs baseline: 5.0251x; 1.0889x over previous
//
#include <hip/hip_runtime.h>
#include <math.h>

#define I_DIM 1024
#define S_DIM 512
#define O_DIM 1024
#define T_DIM 2048
#define B_SZ 4
#define M_ROWS (B_SZ * T_DIM)   // 8192
#define EPSF 1e-6f

// scan chunking: chunk length == GEMM1 BM so pass-1 fuses into GEMM1 epilogue
#define CL 64
#define NCH 32   // NCH*CL == T_DIM

typedef _Float16 f16;
typedef __attribute__((ext_vector_type(8))) _Float16 f16x8;
typedef __attribute__((ext_vector_type(2))) _Float16 f16x2;
typedef __attribute__((ext_vector_type(4))) float f32x4;

__device__ __forceinline__ unsigned short f2h_bits(float f) {
    _Float16 h = (_Float16)f;
    return __builtin_bit_cast(unsigned short, h);
}

// async 16B global -> LDS (wave-uniform LDS base + lane*16; per-thread dest
// = base + tid*16 matches HW layout exactly)
__device__ __forceinline__ void load16_lds(const void* g, void* l) {
    __builtin_amdgcn_global_load_lds((const __attribute__((address_space(1))) void*)g,
                                     (__attribute__((address_space(3))) void*)l,
                                     16, 0, 0);
}

// ---------------------------------------------------------------------------
// prep: fused RMSNorm->fp16  +  B^T (scaled by dts)  +  C^T, one launch.
//   blocks [0, 8192)    : rmsnorm rows
//   blocks [8192, 8704) : B transpose tiles
//   blocks [8704, 9216) : C transpose tiles
// ---------------------------------------------------------------------------
__global__ __launch_bounds__(256)
void prep(const float* __restrict__ u, const float* __restrict__ nw,
          unsigned short* __restrict__ u16,
          const float* __restrict__ Bmat, const float* __restrict__ dt,
          unsigned short* __restrict__ Bt16,
          const float* __restrict__ Cmat, unsigned short* __restrict__ Ct16) {
    __shared__ float tile[32][33];
    const int t = threadIdx.x;
    const int bx = blockIdx.x;

    if (bx < M_ROWS) {
        float4 v = ((const float4*)(u + (size_t)bx * I_DIM))[t];
        float ss = v.x * v.x + v.y * v.y + v.z * v.z + v.w * v.w;
        #pragma unroll
        for (int off = 32; off > 0; off >>= 1) ss += __shfl_down(ss, off, 64);
        if ((t & 63) == 0) tile[0][t >> 6] = ss;
        __syncthreads();
        if (t == 0)
            tile[0][0] = rsqrtf((tile[0][0] + tile[0][1] + tile[0][2] + tile[0][3])
                                * (1.0f / I_DIM) + EPSF);
        __syncthreads();
        const float rs = tile[0][0];
        float4 w = ((const float4*)nw)[t];
        ushort4 o;
        o.x = f2h_bits(v.x * rs * w.x);
        o.y = f2h_bits(v.y * rs * w.y);
        o.z = f2h_bits(v.z * rs * w.z);
        o.w = f2h_bits(v.w * rs * w.w);
        ((ushort4*)(u16 + (size_t)bx * I_DIM))[t] = o;
    } else if (bx < M_ROWS + 512) {
        // B^T with dts fold: Bt16[s, i] = f16(B[i, s] * sigmoid(dt[s]))
        const int tb = bx - M_ROWS;
        const int bs = (tb & 15) * 32;
        const int bi = (tb >> 4) * 32;
        const int tx = t & 31, ty = t >> 5;
        #pragma unroll
        for (int i = ty; i < 32; i += 8)
            tile[i][tx] = Bmat[(size_t)(bi + i) * S_DIM + bs + tx];
        __syncthreads();
        #pragma unroll
        for (int i = ty; i < 32; i += 8) {
            const int s = bs + i;
            const float dts = 1.0f / (1.0f + expf(-dt[s]));
            Bt16[(size_t)s * I_DIM + bi + tx] = f2h_bits(tile[tx][i] * dts);
        }
    } else {
        // C^T: Ct16[o, s] = f16(C[s, o])
        const int tb = bx - M_ROWS - 512;
        const int bo = (tb & 31) * 32;
        const int bs = (tb >> 5) * 32;
        const int tx = t & 31, ty = t >> 5;
        #pragma unroll
        for (int i = ty; i < 32; i += 8)
            tile[i][tx] = Cmat[(size_t)(bs + i) * O_DIM + bo + tx];
        __syncthreads();
        #pragma unroll
        for (int i = ty; i < 32; i += 8)
            Ct16[(size_t)(bo + i) * S_DIM + bs + tx] = f2h_bits(tile[tx][i]);
    }
}

// ---------------------------------------------------------------------------
// fp16 MFMA GEMM, 64x128 tile, BK=32, 4 waves (each 64 rows x 32 cols),
// 2-phase double-buffered LDS with counted vmcnt(3). Grid: GEMM1 512 blocks
// (2/CU), GEMM2 1024 (4/CU) -> cross-block wave overlap hides staging.
// CHFIN: fused scan pass-1 — chunk-final_s = sum_j a_s^(63-j) * acc_row_j
// computed from fp32 acc (wave layout 1xN puts all 64 rows in each wave).
// ---------------------------------------------------------------------------
template<bool BIAS, bool CHFIN, typename OUT>
__global__ __launch_bounds__(256)
void mfma_gemm_f16(const f16* __restrict__ A, const f16* __restrict__ Bt,
                   OUT* __restrict__ Cout, int M, int N, int K, int ldb,
                   const float* __restrict__ bias,
                   const float* __restrict__ dt, const float* __restrict__ Avec,
                   float* __restrict__ chlast) {
    constexpr int BM = 64, BN = 128;
    __shared__ f16 As[2][BM * 32];        // 8 KB
    __shared__ f16 Bs[2][BN * 32];        // 16 KB
    const int t = threadIdx.x;

    // XCD swizzle (nwg % 8 == 0 for both grids); consecutive logical bids
    // (same A panel) land on the same XCD -> L2 hits for A re-reads.
    int bid = blockIdx.y * gridDim.x + blockIdx.x;
    const int nwg = gridDim.x * gridDim.y;
    const int cpx = nwg >> 3;
    bid = (bid & 7) * cpx + (bid >> 3);
    const int n0 = (bid % gridDim.x) * BN;
    const int m0 = (bid / gridDim.x) * BM;

    const int wid = t >> 6, lane = t & 63;
    const int wn = wid * 32;              // wave col base (1x4 wave layout)
    const int lr = lane & 15, kg = lane >> 4;

    f32x4 acc[4][2];
    #pragma unroll
    for (int i = 0; i < 4; ++i)
        #pragma unroll
        for (int j = 0; j < 2; ++j) acc[i][j] = (f32x4){0.f, 0.f, 0.f, 0.f};

    const size_t arow = (size_t)(m0 + (t >> 2)) * K + (t & 3) * 8;
    const size_t brow = (size_t)(n0 + (t >> 2)) * ldb + (t & 3) * 8;

    auto stage = [&](int k0, int bsel) {
        load16_lds(A + arow + k0, &As[bsel][t * 8]);
        load16_lds(Bt + brow + k0, &Bs[bsel][t * 8]);
        load16_lds(Bt + brow + (size_t)64 * ldb + k0, &Bs[bsel][2048 + t * 8]);
    };

    const int nk = K >> 5;
    stage(0, 0);
    for (int kt = 0; kt < nk; ++kt) {
        const int cur = kt & 1;
        if (kt + 1 < nk) {
            stage((kt + 1) << 5, cur ^ 1);        // prefetch stays in flight
            asm volatile("s_waitcnt vmcnt(3)");   // my 3 current-tile loads done
        } else {
            asm volatile("s_waitcnt vmcnt(0)");
        }
        __builtin_amdgcn_s_barrier();
        __builtin_amdgcn_sched_barrier(0);        // keep ds_reads below barrier

        f16x8 af[4], bfr[2];
        #pragma unroll
        for (int m = 0; m < 4; ++m)
            af[m] = *(const f16x8*)&As[cur][(m * 16 + lr) * 32 + kg * 8];
        #pragma unroll
        for (int n = 0; n < 2; ++n)
            bfr[n] = *(const f16x8*)&Bs[cur][(wn + n * 16 + lr) * 32 + kg * 8];
        #pragma unroll
        for (int m = 0; m < 4; ++m)
            #pragma unroll
            for (int n = 0; n < 2; ++n)
                acc[m][n] = __builtin_amdgcn_mfma_f32_16x16x32_f16(af[m], bfr[n], acc[m][n], 0, 0, 0);
        __builtin_amdgcn_s_barrier();
    }

    // C/D layout: col = lane&15, row = (lane>>4)*4 + reg
    #pragma unroll
    for (int m = 0; m < 4; ++m) {
        const int row = m0 + m * 16 + kg * 4;
        #pragma unroll
        for (int n = 0; n < 2; ++n) {
            const int col = n0 + wn + n * 16 + lr;
            const float b = BIAS ? bias[col] : 0.0f;
            #pragma unroll
            for (int j = 0; j < 4; ++j) {
                if constexpr (sizeof(OUT) == 4)
                    Cout[(size_t)(row + j) * N + col] = (OUT)(acc[m][n][j] + b);
                else
                    Cout[(size_t)(row + j) * N + col] = (OUT)(_Float16)acc[m][n][j];
            }
        }
    }

    if constexpr (CHFIN) {
        // chunk-final for this block's 64 t-rows: sum_r a^(63-r) * v_r
        const int cb = m0 >> 11;              // batch
        const int cc = (m0 >> 6) & (NCH - 1); // chunk
        #pragma unroll
        for (int n = 0; n < 2; ++n) {
            const int s = n0 + wn + n * 16 + lr;
            const float dts = 1.0f / (1.0f + expf(-dt[s]));
            const float e = dts * fabsf(Avec[s]);
            const float ainv = expf(e);       // a^-1 (a = exp(-e) <= 1)
            float partial = 0.f;
            #pragma unroll
            for (int m = 0; m < 4; ++m) {
                float wgt = expf(-e * (float)(63 - m * 16 - kg * 4));
                #pragma unroll
                for (int j = 0; j < 4; ++j) {   // row = m*16+kg*4+j, wgt = a^(63-row) <= 1
                    partial = fmaf(wgt, acc[m][n][j], partial);
                    wgt *= ainv;
                }
            }
            partial += __shfl_xor(partial, 16, 64);
            partial += __shfl_xor(partial, 32, 64);
            if (kg == 0)
                chlast[(size_t)(cb * NCH + cc) * S_DIM + s] = partial;
        }
    }
}

// ---------------------------------------------------------------------------
// Scan pass 2: per (b, chunk, s-pair) — self-computed carry prefix over
// chunk finals (<=31 L2-hot FMA), re-scan chunk from fp16 up, emit fp16 x
// and final state. dts is pre-folded into up.
// ---------------------------------------------------------------------------
__global__ __launch_bounds__(256)
void scan_apply(const f16* __restrict__ up, const float* __restrict__ chlast,
                const float* __restrict__ dt, const float* __restrict__ Avec,
                unsigned* __restrict__ x32, float* __restrict__ xlast) {
    const int gid = blockIdx.x * 256 + threadIdx.x;
    const int s2 = gid & 255;
    const int c = (gid >> 8) & (NCH - 1);
    const int b = gid >> 13;
    const int s0 = s2 * 2;
    const float dts0 = 1.0f / (1.0f + expf(-dt[s0]));
    const float dts1 = 1.0f / (1.0f + expf(-dt[s0 + 1]));
    const float ab0 = fabsf(Avec[s0]), ab1 = fabsf(Avec[s0 + 1]);
    const float a0 = expf(-dts0 * ab0);
    const float a1 = expf(-dts1 * ab1);
    const float aCL0 = expf(-dts0 * ab0 * (float)CL);
    const float aCL1 = expf(-dts1 * ab1 * (float)CL);

    // carry prefix over chunk finals 0..c-1 (c uniform per block)
    const float2* ch = (const float2*)chlast;
    float cy0 = 0.f, cy1 = 0.f;
    for (int j = 0; j < c; ++j) {
        float2 f = ch[(size_t)(b * NCH + j) * 256 + s2];
        cy0 = fmaf(aCL0, cy0, f.x);
        cy1 = fmaf(aCL1, cy1, f.y);
    }

    const unsigned* up32 = (const unsigned*)up;
    const size_t base = (size_t)(b * T_DIM + c * CL) * 256 + s2;
    unsigned v[CL];
    #pragma unroll
    for (int j = 0; j < CL; ++j) v[j] = up32[base + (size_t)j * 256];
    float x0 = cy0, x1 = cy1;
    #pragma unroll
    for (int j = 0; j < CL; ++j) {
        f16x2 h = __builtin_bit_cast(f16x2, v[j]);
        x0 = fmaf(a0, x0, (float)h.x);
        x1 = fmaf(a1, x1, (float)h.y);
        f16x2 o; o.x = (_Float16)x0; o.y = (_Float16)x1;
        v[j] = __builtin_bit_cast(unsigned, o);
    }
    #pragma unroll
    for (int j = 0; j < CL; ++j) x32[base + (size_t)j * 256] = v[j];
    if (c == NCH - 1) ((float2*)xlast)[b * 256 + s2] = make_float2(x0, x1);
}

// ---------------------------------------------------------------------------
extern "C" void kernel_launch(void* const* d_in, const int* in_sizes, int n_in,
                              void* d_out, int out_size, void* d_ws, size_t ws_size,
                              hipStream_t stream) {
    const float* u    = (const float*)d_in[0];   // [B,T,I]
    const float* dt   = (const float*)d_in[1];   // [S]
    const float* Avec = (const float*)d_in[2];   // [S]
    const float* Bmat = (const float*)d_in[3];   // [I,S]
    const float* Cmat = (const float*)d_in[4];   // [S,O]
    const float* Dvec = (const float*)d_in[5];   // [O]
    const float* nw   = (const float*)d_in[6];   // [I]

    float* y     = (float*)d_out;                      // [B,T,O] fp32
    float* xlast = y + (size_t)M_ROWS * O_DIM;         // [B,S]   fp32

    // workspace layout (~36 MB)
    char* w = (char*)d_ws;
    unsigned short* u16    = (unsigned short*)(w);               // [8192,1024] f16
    f16*            up16   = (f16*)(w + 16777216);               // [8192,512]  f16
    f16*            x16    = (f16*)(w + 25165824);               // [8192,512]  f16
    unsigned short* Bt16   = (unsigned short*)(w + 33554432);    // [512,1024]  f16 B^T (dts-scaled)
    unsigned short* Ct16   = (unsigned short*)(w + 34603008);    // [1024,512]  f16 C^T
    float*          chlast = (float*)(w + 35651584);             // [B,NCH,S] fp32 (256 KB)

    // 1. fused prep: rmsnorm->fp16 + B^T(dts) + C^T
    prep<<<M_ROWS + 512 + 512, 256, 0, stream>>>(u, nw, u16, Bmat, dt, Bt16, Cmat, Ct16);

    // 2. GEMM1 (+ fused scan pass-1): up16 = u16 @ (B*dts); chlast from acc
    dim3 g1(S_DIM / 128, M_ROWS / 64);   // 4 x 128 = 512 blocks
    mfma_gemm_f16<false, true, f16><<<g1, 256, 0, stream>>>(
        (const f16*)u16, (const f16*)Bt16, up16, M_ROWS, S_DIM, I_DIM, I_DIM,
        nullptr, dt, Avec, chlast);

    // 3. scan pass 2: carry + re-scan, emit fp16 x + final state
    scan_apply<<<(B_SZ * NCH * 256) / 256, 256, 0, stream>>>(up16, chlast, dt, Avec,
                                                             (unsigned*)x16, xlast);

    // 4. GEMM2: y = x16 @ C + D   (M=8192, N=1024, K=512)
    dim3 g2(O_DIM / 128, M_ROWS / 64);   // 8 x 128 = 1024 blocks
    mfma_gemm_f16<true, false, float><<<g2, 256, 0, stream>>>(
        x16, (const f16*)Ct16, y, M_ROWS, O_DIM, S_DIM, S_DIM,
        Dvec, nullptr, nullptr, nullptr);
}

// Round 6
// 64.440 us; speedup vs baseline: 5.0744x; 1.0098x over previous
//
#include <hip/hip_runtime.h>
#include <math.h>

#define I_DIM 1024
#define S_DIM 512
#define O_DIM 1024
#define T_DIM 2048
#define B_SZ 4
#define M_ROWS (B_SZ * T_DIM)   // 8192
#define EPSF 1e-6f

// scan chunking: chunk length == GEMM BM (64)
#define CL 64
#define NCH 32   // NCH*CL == T_DIM

typedef _Float16 f16;
typedef __attribute__((ext_vector_type(8))) _Float16 f16x8;
typedef __attribute__((ext_vector_type(2))) _Float16 f16x2;
typedef __attribute__((ext_vector_type(4))) float f32x4;

__device__ __forceinline__ unsigned short f2h_bits(float f) {
    _Float16 h = (_Float16)f;
    return __builtin_bit_cast(unsigned short, h);
}

// async 16B global -> LDS (wave-uniform LDS base + lane*16; per-thread dest
// = base + tid*16 matches HW layout exactly -> LINEAR dest only)
__device__ __forceinline__ void load16_lds(const void* g, void* l) {
    __builtin_amdgcn_global_load_lds((const __attribute__((address_space(1))) void*)g,
                                     (__attribute__((address_space(3))) void*)l,
                                     16, 0, 0);
}

// ---------------------------------------------------------------------------
// prep: weight transposes only.
//   blocks [0,512)    : Bt16[s,i] = f16( B[i,s] * sigmoid(dt[s]) * nw[i] )
//   blocks [512,1024) : Ct16[o,s] = f16( C[s,o] )
// ---------------------------------------------------------------------------
__global__ __launch_bounds__(256)
void prep_w(const float* __restrict__ Bmat, const float* __restrict__ dt,
            const float* __restrict__ nw, unsigned short* __restrict__ Bt16,
            const float* __restrict__ Cmat, unsigned short* __restrict__ Ct16) {
    __shared__ float tile[32][33];
    const int t = threadIdx.x;
    const int tx = t & 31, ty = t >> 5;
    const int bx = blockIdx.x;
    if (bx < 512) {
        const int bs = (bx & 15) * 32;   // s block
        const int bi = (bx >> 4) * 32;   // i block
        #pragma unroll
        for (int i = ty; i < 32; i += 8)
            tile[i][tx] = Bmat[(size_t)(bi + i) * S_DIM + bs + tx];
        __syncthreads();
        const float w = nw[bi + tx];
        #pragma unroll
        for (int i = ty; i < 32; i += 8) {
            const int s = bs + i;
            const float dts = 1.0f / (1.0f + expf(-dt[s]));
            Bt16[(size_t)s * I_DIM + bi + tx] = f2h_bits(tile[tx][i] * dts * w);
        }
    } else {
        const int tb = bx - 512;
        const int bo = (tb & 31) * 32;   // o block
        const int bs = (tb >> 5) * 32;   // s block
        #pragma unroll
        for (int i = ty; i < 32; i += 8)
            tile[i][tx] = Cmat[(size_t)(bs + i) * O_DIM + bo + tx];
        __syncthreads();
        #pragma unroll
        for (int i = ty; i < 32; i += 8)
            Ct16[(size_t)(bo + i) * S_DIM + bs + tx] = f2h_bits(tile[tx][i]);
    }
}

// ---------------------------------------------------------------------------
// GEMM1 fused with RMSNorm + scan pass-1.
// up[m,s] = rs[m] * sum_i f16(u[m,i]) * f16(nw[i]*B[i,s]*dts[s])
// A-side reg-staged from fp32 u (cvt->f16 + sumsq same pass); rs at epilogue.
// As rows padded to 80B (conflict-free frag reads). B-side global_load_lds.
// chfin: chunk-final_s = sum_r a_s^(63-r) * up[m0+r, s]  (fp32, fused).
// ---------------------------------------------------------------------------
__global__ __launch_bounds__(256)
void gemm1_rms_chfin(const float* __restrict__ U, const f16* __restrict__ Bt,
                     f16* __restrict__ up, float* __restrict__ chlast,
                     const float* __restrict__ dt, const float* __restrict__ Avec) {
    constexpr int K = I_DIM, N = S_DIM, LDA = 80, NK = K / 32;
    __shared__ __align__(16) unsigned char AsB[2][64 * LDA];   // 10 KB
    __shared__ f16 Bs[2][128 * 32];                            // 16 KB
    __shared__ float rsbuf[64];
    const int t = threadIdx.x;

    // hw blockIdx -> tile id, chunked per XCD (contiguous tiles share A panel)
    int bid = blockIdx.x;                 // grid = 512
    bid = (bid & 7) * 64 + (bid >> 3);
    const int n0 = (bid & 3) * 128;       // 4 n-blocks
    const int m0 = (bid >> 2) * 64;       // 128 m-blocks
    const int wid = t >> 6, lane = t & 63;
    const int wn = wid * 32, lr = lane & 15, kg = lane >> 4;

    const float* aptr = U + (size_t)(m0 + (t >> 2)) * K + (t & 3) * 8;
    const f16*  bptr = Bt + (size_t)(n0 + (t >> 2)) * K + (t & 3) * 8;
    unsigned char* adst0 = &AsB[0][(t >> 2) * LDA + (t & 3) * 16];
    unsigned char* adst1 = &AsB[1][(t >> 2) * LDA + (t & 3) * 16];

    float ss = 0.f;
    f32x4 acc[4][2];
    #pragma unroll
    for (int i = 0; i < 4; ++i)
        #pragma unroll
        for (int j = 0; j < 2; ++j) acc[i][j] = (f32x4){0.f, 0.f, 0.f, 0.f};

    float4 ra, rb;
    auto cvt_write = [&](unsigned char* dst) {
        ss += ra.x * ra.x + ra.y * ra.y + ra.z * ra.z + ra.w * ra.w
            + rb.x * rb.x + rb.y * rb.y + rb.z * rb.z + rb.w * rb.w;
        f16x8 h = { (_Float16)ra.x, (_Float16)ra.y, (_Float16)ra.z, (_Float16)ra.w,
                    (_Float16)rb.x, (_Float16)rb.y, (_Float16)rb.z, (_Float16)rb.w };
        *(f16x8*)dst = h;
    };

    // prologue: stage tile 0
    load16_lds(bptr, &Bs[0][t * 8]);
    load16_lds(bptr + (size_t)64 * K, &Bs[0][2048 + t * 8]);
    ra = *(const float4*)(aptr);
    rb = *(const float4*)(aptr + 4);
    cvt_write(adst0);
    __syncthreads();

    for (int kt = 0; kt < NK; ++kt) {
        const int cur = kt & 1;
        if (kt + 1 < NK) {
            const int k1 = (kt + 1) * 32;
            load16_lds(bptr + k1, &Bs[cur ^ 1][t * 8]);
            load16_lds(bptr + (size_t)64 * K + k1, &Bs[cur ^ 1][2048 + t * 8]);
            ra = *(const float4*)(aptr + k1);
            rb = *(const float4*)(aptr + k1 + 4);
        }
        f16x8 af[4], bf[2];
        #pragma unroll
        for (int m = 0; m < 4; ++m)
            af[m] = *(const f16x8*)&AsB[cur][(m * 16 + lr) * LDA + kg * 16];
        #pragma unroll
        for (int n = 0; n < 2; ++n)
            bf[n] = *(const f16x8*)&Bs[cur][(wn + n * 16 + lr) * 32 + kg * 8];
        #pragma unroll
        for (int m = 0; m < 4; ++m)
            #pragma unroll
            for (int n = 0; n < 2; ++n)
                acc[m][n] = __builtin_amdgcn_mfma_f32_16x16x32_f16(af[m], bf[n], acc[m][n], 0, 0, 0);
        if (kt + 1 < NK) cvt_write(cur == 0 ? adst1 : adst0);   // overlaps MFMA latency
        __syncthreads();
    }

    // rs per row: reduce sumsq across the 4 threads sharing a row
    ss += __shfl_xor(ss, 1, 64);
    ss += __shfl_xor(ss, 2, 64);
    if ((t & 3) == 0) rsbuf[t >> 2] = rsqrtf(ss * (1.0f / K) + EPSF);
    __syncthreads();

    // epilogue: up = rs*acc (f16) + fused chunk-final (fp32)
    const int cb = m0 >> 11;               // batch
    const int cc = (m0 >> 6) & (NCH - 1);  // chunk
    #pragma unroll
    for (int n = 0; n < 2; ++n) {
        const int col = n0 + wn + n * 16 + lr;
        const float dts = 1.0f / (1.0f + expf(-dt[col]));
        const float e = dts * fabsf(Avec[col]);
        const float ainv = expf(e);        // a^-1
        float partial = 0.f;
        #pragma unroll
        for (int m = 0; m < 4; ++m) {
            const int row = m * 16 + kg * 4;
            f32x4 rs4 = *(const f32x4*)&rsbuf[row];
            float wgt = expf(-e * (float)(63 - row));   // a^(63-row)
            #pragma unroll
            for (int j = 0; j < 4; ++j) {
                const float val = rs4[j] * acc[m][n][j];
                up[(size_t)(m0 + row + j) * N + col] = (_Float16)val;
                partial = fmaf(wgt, val, partial);
                wgt *= ainv;
            }
        }
        partial += __shfl_xor(partial, 16, 64);
        partial += __shfl_xor(partial, 32, 64);
        if (kg == 0)
            chlast[(size_t)(cb * NCH + cc) * S_DIM + col] = partial;
    }
}

// ---------------------------------------------------------------------------
// GEMM2 fused with scan pass-2:  y = x @ C + D,  x_t = a*x_{t-1} + up_t.
// Each block: carry prefix from chunk finals -> 64-step scan of its chunk ->
// x-tile (64x512 f16) into resident LDS (XOR-swizzled) -> K-loop with B-only
// double-buffered staging. xlast written by last-chunk blocks (dup, same val).
// ---------------------------------------------------------------------------
__global__ __launch_bounds__(256)
void gemm2_scan(const f16* __restrict__ upb, const float* __restrict__ chlast,
                const f16* __restrict__ Ct, const float* __restrict__ Dvec,
                const float* __restrict__ dt, const float* __restrict__ Avec,
                float* __restrict__ y, float* __restrict__ xlast) {
    constexpr int K = S_DIM, N = O_DIM, NK = K / 32;   // 16 k-steps
    __shared__ __align__(16) unsigned char As[64 * 1024];   // 64 KB x-tile
    __shared__ f16 Bs[2][128 * 32];                         // 16 KB
    const int t = threadIdx.x;

    int bid = blockIdx.x;                 // grid = 1024
    bid = (bid & 7) * 128 + (bid >> 3);
    const int n0 = (bid & 7) * 128;       // 8 n-blocks
    const int m0 = (bid >> 3) * 64;       // 128 m-blocks (= b*32 + chunk)
    const int wid = t >> 6, lane = t & 63;
    const int wn = wid * 32, lr = lane & 15, kg = lane >> 4;

    // stage B(0) early; latency hides under carry+scan
    const f16* bptr = Ct + (size_t)(n0 + (t >> 2)) * K + (t & 3) * 8;
    load16_lds(bptr, &Bs[0][t * 8]);
    load16_lds(bptr + (size_t)64 * K, &Bs[0][2048 + t * 8]);

    // ---- carry prefix over chunk finals ----
    const int cc = (m0 >> 6) & (NCH - 1);
    const int cb = m0 >> 11;
    const int s0 = 2 * t;
    const float dts0 = 1.0f / (1.0f + expf(-dt[s0]));
    const float dts1 = 1.0f / (1.0f + expf(-dt[s0 + 1]));
    const float ab0 = fabsf(Avec[s0]), ab1 = fabsf(Avec[s0 + 1]);
    const float g0 = expf(-dts0 * ab0);
    const float g1 = expf(-dts1 * ab1);
    const float gCL0 = expf(-dts0 * ab0 * (float)CL);
    const float gCL1 = expf(-dts1 * ab1 * (float)CL);
    const float2* ch = (const float2*)chlast;
    float cy0 = 0.f, cy1 = 0.f;
    for (int j = 0; j < cc; ++j) {
        float2 f = ch[(size_t)(cb * NCH + j) * 256 + t];
        cy0 = fmaf(gCL0, cy0, f.x);
        cy1 = fmaf(gCL1, cy1, f.y);
    }

    // ---- load chunk + scan + swizzled LDS write ----
    const unsigned* up32 = (const unsigned*)upb;
    const size_t ub = (size_t)m0 * 256 + t;
    unsigned v[CL];
    #pragma unroll
    for (int j = 0; j < CL; ++j) v[j] = up32[ub + (size_t)j * 256];
    float x0 = cy0, x1 = cy1;
    #pragma unroll
    for (int j = 0; j < CL; ++j) {
        f16x2 h = __builtin_bit_cast(f16x2, v[j]);
        x0 = fmaf(g0, x0, (float)h.x);
        x1 = fmaf(g1, x1, (float)h.y);
        f16x2 o; o.x = (_Float16)x0; o.y = (_Float16)x1;
        v[j] = __builtin_bit_cast(unsigned, o);
    }
    #pragma unroll
    for (int j = 0; j < CL; ++j)
        *(unsigned*)&As[j * 1024 + ((t * 4) ^ ((j & 7) << 4))] = v[j];
    if (cc == NCH - 1)
        ((float2*)xlast)[cb * 256 + t] = make_float2(x0, x1);   // dup across n-blocks, same value
    __syncthreads();

    // ---- K-loop: A resident in LDS, B double-buffered ----
    f32x4 acc[4][2];
    #pragma unroll
    for (int i = 0; i < 4; ++i)
        #pragma unroll
        for (int j = 0; j < 2; ++j) acc[i][j] = (f32x4){0.f, 0.f, 0.f, 0.f};

    const int swz = (lr & 7) << 4;        // row&7 == lr&7 for row = m*16+lr
    for (int kt = 0; kt < NK; ++kt) {
        const int cur = kt & 1;
        if (kt + 1 < NK) {
            const int k1 = (kt + 1) * 32;
            load16_lds(bptr + k1, &Bs[cur ^ 1][t * 8]);
            load16_lds(bptr + (size_t)64 * K + k1, &Bs[cur ^ 1][2048 + t * 8]);
        }
        f16x8 af[4], bf[2];
        #pragma unroll
        for (int m = 0; m < 4; ++m)
            af[m] = *(const f16x8*)&As[(m * 16 + lr) * 1024 + ((kt * 64 + kg * 16) ^ swz)];
        #pragma unroll
        for (int n = 0; n < 2; ++n)
            bf[n] = *(const f16x8*)&Bs[cur][(wn + n * 16 + lr) * 32 + kg * 8];
        #pragma unroll
        for (int m = 0; m < 4; ++m)
            #pragma unroll
            for (int n = 0; n < 2; ++n)
                acc[m][n] = __builtin_amdgcn_mfma_f32_16x16x32_f16(af[m], bf[n], acc[m][n], 0, 0, 0);
        __syncthreads();
    }

    // epilogue: y = acc + D
    #pragma unroll
    for (int n = 0; n < 2; ++n) {
        const int col = n0 + wn + n * 16 + lr;
        const float dv = Dvec[col];
        #pragma unroll
        for (int m = 0; m < 4; ++m) {
            const int row = m0 + m * 16 + kg * 4;
            #pragma unroll
            for (int j = 0; j < 4; ++j)
                y[(size_t)(row + j) * N + col] = acc[m][n][j] + dv;
        }
    }
}

// ---------------------------------------------------------------------------
extern "C" void kernel_launch(void* const* d_in, const int* in_sizes, int n_in,
                              void* d_out, int out_size, void* d_ws, size_t ws_size,
                              hipStream_t stream) {
    const float* u    = (const float*)d_in[0];   // [B,T,I]
    const float* dt   = (const float*)d_in[1];   // [S]
    const float* Avec = (const float*)d_in[2];   // [S]
    const float* Bmat = (const float*)d_in[3];   // [I,S]
    const float* Cmat = (const float*)d_in[4];   // [S,O]
    const float* Dvec = (const float*)d_in[5];   // [O]
    const float* nw   = (const float*)d_in[6];   // [I]

    float* y     = (float*)d_out;                      // [B,T,O] fp32
    float* xlast = y + (size_t)M_ROWS * O_DIM;         // [B,S]   fp32

    // workspace (~10.7 MB)
    char* w = (char*)d_ws;
    f16*            up16   = (f16*)(w);                          // [8192,512] f16
    unsigned short* Bt16   = (unsigned short*)(w + 8388608);     // [512,1024] f16 (dts,nw folded)
    unsigned short* Ct16   = (unsigned short*)(w + 9437184);     // [1024,512] f16
    float*          chlast = (float*)(w + 10485760);             // [B,NCH,S] fp32

    // 1. weight transposes
    prep_w<<<1024, 256, 0, stream>>>(Bmat, dt, nw, Bt16, Cmat, Ct16);

    // 2. GEMM1 (+rmsnorm +chunk-finals): up16, chlast
    gemm1_rms_chfin<<<512, 256, 0, stream>>>(u, (const f16*)Bt16, up16, chlast, dt, Avec);

    // 3. GEMM2 (+carry +scan): y, xlast
    gemm2_scan<<<1024, 256, 0, stream>>>(up16, chlast, (const f16*)Ct16, Dvec,
                                         dt, Avec, y, xlast);
}